// Round 4
// baseline (2708.874 us; speedup 1.0000x reference)
//
#include <hip/hip_runtime.h>

typedef unsigned short u16;
typedef unsigned int u32;
typedef __attribute__((ext_vector_type(4))) float f32x4;
typedef __attribute__((ext_vector_type(8))) short short8;  // bf16 bits in i16 lanes

constexpr int TT = 2048;   // tokens = B*S
constexpr int HH = 2048;   // hidden
constexpr int FF = 7168;   // ffn
constexpr int RR = 32;     // lora rank
constexpr int KT = 2;      // top-k

__device__ __forceinline__ float bf2f(u16 v) {
  union { u32 u; float f; } w; w.u = ((u32)v) << 16; return w.f;
}
__device__ __forceinline__ u16 f2bf(float f) {
  union { float f; u32 u; } w; w.f = f;
  u32 u = w.u;
  return (u16)((u + 0x7FFFu + ((u >> 16) & 1u)) >> 16);
}

// ---------------- f32 -> bf16 conversion (grid-stride, float4) ----------------
__global__ __launch_bounds__(256) void cvt_kernel(
    const float* __restrict__ src, u16* __restrict__ dst, int n4) {
  int stride = gridDim.x * 256;
  for (int i = blockIdx.x * 256 + threadIdx.x; i < n4; i += stride) {
    float4 v = ((const float4*)src)[i];
    ushort4 o;
    o.x = f2bf(v.x); o.y = f2bf(v.y); o.z = f2bf(v.z); o.w = f2bf(v.w);
    ((ushort4*)dst)[i] = o;
  }
}

// ---------------- gating: logits -> top2 -> weights (f32) ----------------
__global__ __launch_bounds__(64) void gating_kernel(
    const float* __restrict__ X, const float* __restrict__ Wg,
    int* __restrict__ sel, float* __restrict__ rw) {
  int t = blockIdx.x;
  int lane = threadIdx.x;
  const float* x = X + (size_t)t * HH;
  float acc[8] = {};
  for (int h = lane; h < HH; h += 64) {
    float xv = x[h];
#pragma unroll
    for (int e = 0; e < 8; e++) acc[e] += xv * Wg[e * HH + h];
  }
#pragma unroll
  for (int e = 0; e < 8; e++)
    for (int off = 32; off; off >>= 1) acc[e] += __shfl_down(acc[e], off);
  if (lane == 0) {
    int b0 = 0; float l0 = acc[0];
    for (int e = 1; e < 8; e++) if (acc[e] > l0) { l0 = acc[e]; b0 = e; }
    int b1 = -1; float l1 = 0.f;
    for (int e = 0; e < 8; e++) {
      if (e == b0) continue;
      if (b1 < 0 || acc[e] > l1) { l1 = acc[e]; b1 = e; }  // b1 always in [0,7]
    }
    float p = 1.f / (1.f + __expf(l1 - l0));
    sel[t * 2 + 0] = b0; sel[t * 2 + 1] = b1;
    rw[t * 2 + 0] = p;   rw[t * 2 + 1] = 1.f - p;
  }
}

// ---------------- a1/a3 for selected experts (f32) ----------------
__global__ __launch_bounds__(256) void a13_kernel(
    const float* __restrict__ X, const float* __restrict__ A1, const float* __restrict__ A3,
    const int* __restrict__ sel, float* __restrict__ a1o, float* __restrict__ a3o) {
  int t = blockIdx.x >> 1, k = blockIdx.x & 1;
  int e = sel[t * 2 + k] & 7;
  __shared__ __align__(16) float sx[HH];
  const float* src = X + (size_t)t * HH;
#pragma unroll
  for (int it = 0; it < 2; it++) {
    int i = it * 256 + threadIdx.x;       // i < HH/4 = 512
    ((float4*)sx)[i] = ((const float4*)src)[i];
  }
  __syncthreads();
  int wave = threadIdx.x >> 6, lane = threadIdx.x & 63;
  for (int j = 0; j < 16; j++) {
    int rr = wave * 16 + j;               // 0..31 -> a1, 32..63 -> a3
    const float* Arow = (rr < 32 ? A1 : A3) + ((size_t)e * RR + (rr & 31)) * HH;
    float s = 0.f;
#pragma unroll
    for (int i = 0; i < 8; i++) {         // 8 iters of float4
      int c = lane + 64 * i;              // < 512
      float4 a = ((const float4*)Arow)[c];
      float4 b = ((const float4*)sx)[c];
      s += a.x * b.x + a.y * b.y + a.z * b.z + a.w * b.w;
    }
    for (int off = 32; off; off >>= 1) s += __shfl_down(s, off);
    if (lane == 0) {
      float* dst = (rr < 32) ? a1o : a3o;
      dst[((size_t)t * KT + k) * RR + (rr & 31)] = s;
    }
  }
}

// ---------------- MFMA GEMM: C[M,N] = A[M,K] * Bm[N,K]^T (bf16 in) ----------------
// 128x128 tile, BK=64, 256 threads (4 waves, 2x2 of 64x64), 16x16x32 bf16 MFMA.
// Register-mediated staging with XOR swizzle on the k-chunk (conflict-free reads).
__global__ __launch_bounds__(256) void gemm_bt(
    const u16* A0, const u16* A1p,
    const u16* B0, const u16* B1p,
    u16* Cb0, u16* Cb1, float* Cf0, float* Cf1,
    int N, int Kd, int out_bf16) {
  const u16* A  = blockIdx.z ? A1p : A0;
  const u16* Bm = blockIdx.z ? B1p : B0;
  u16* Cb       = blockIdx.z ? Cb1 : Cb0;
  float* Cf     = blockIdx.z ? Cf1 : Cf0;

  __shared__ __align__(16) u16 As[128 * 64];
  __shared__ __align__(16) u16 Bs[128 * 64];

  int tid = threadIdx.x;
  int tn = blockIdx.x * 128;
  int tm = blockIdx.y * 128;
  int lane = tid & 63;
  int wave = tid >> 6;
  int wm = (wave >> 1) * 64, wn = (wave & 1) * 64;
  const int r15 = lane & 15, q = lane >> 4;

  f32x4 acc[4][4] = {};

  for (int k0 = 0; k0 < Kd; k0 += 64) {
    uint4 ra[4], rb[4];
#pragma unroll
    for (int it = 0; it < 4; it++) {
      int c = it * 256 + tid;
      int row = c >> 3, c8 = c & 7;
      int scol = ((c8 ^ (row & 7)) << 3);  // LDS chunk (row,c8) holds global chunk c8^(row&7)
      ra[it] = *(const uint4*)(A + (size_t)(tm + row) * Kd + (k0 + scol));
      rb[it] = *(const uint4*)(Bm + (size_t)(tn + row) * Kd + (k0 + scol));
    }
    __syncthreads();
#pragma unroll
    for (int it = 0; it < 4; it++) {
      int c = it * 256 + tid;
      *(uint4*)(As + c * 8) = ra[it];
      *(uint4*)(Bs + c * 8) = rb[it];
    }
    __syncthreads();
#pragma unroll
    for (int kk = 0; kk < 2; kk++) {
      short8 af[4], bfr[4];
#pragma unroll
      for (int mi = 0; mi < 4; mi++) {
        int row = wm + mi * 16 + r15;
        int kc = (kk * 4 + q) ^ (row & 7);
        af[mi] = *(const short8*)(As + row * 64 + kc * 8);
      }
#pragma unroll
      for (int ni = 0; ni < 4; ni++) {
        int row = wn + ni * 16 + r15;
        int kc = (kk * 4 + q) ^ (row & 7);
        bfr[ni] = *(const short8*)(Bs + row * 64 + kc * 8);
      }
#pragma unroll
      for (int mi = 0; mi < 4; mi++)
#pragma unroll
        for (int ni = 0; ni < 4; ni++)
          acc[mi][ni] = __builtin_amdgcn_mfma_f32_16x16x32_bf16(af[mi], bfr[ni], acc[mi][ni], 0, 0, 0);
    }
  }
  // epilogue: C/D layout col=lane&15, row=(lane>>4)*4+i
#pragma unroll
  for (int mi = 0; mi < 4; mi++)
#pragma unroll
    for (int ni = 0; ni < 4; ni++)
#pragma unroll
      for (int i = 0; i < 4; i++) {
        int r = tm + wm + mi * 16 + q * 4 + i;
        int cc = tn + wn + ni * 16 + r15;
        float v = acc[mi][ni][i];
        if (out_bf16) Cb[(size_t)r * N + cc] = f2bf(v);
        else          Cf[(size_t)r * N + cc] = v;
      }
}

// ---------------- silu(Y1+lora1)*(Y3+lora3) -> X2 (bf16) ----------------
__global__ __launch_bounds__(256) void silu_kernel(
    const u16* __restrict__ Y1, const u16* __restrict__ Y3,
    const float* __restrict__ B1, const float* __restrict__ B3,
    const float* __restrict__ a1, const float* __restrict__ a3,
    const int* __restrict__ sel, u16* __restrict__ X2) {
  int t = blockIdx.x;
  __shared__ float sa1[64], sa3[64];
  __shared__ int se[2];
  if (threadIdx.x < 64) {
    sa1[threadIdx.x] = a1[(size_t)t * 64 + threadIdx.x];
    sa3[threadIdx.x] = a3[(size_t)t * 64 + threadIdx.x];
  }
  if (threadIdx.x < 2) se[threadIdx.x] = sel[t * 2 + threadIdx.x] & 7;
  __syncthreads();
  for (int f = threadIdx.x; f < FF; f += 256) {
    float y1 = bf2f(Y1[(size_t)t * FF + f]);
    float y3 = bf2f(Y3[(size_t)t * FF + f]);
#pragma unroll
    for (int k = 0; k < 2; k++) {
      int e = se[k];
      const float4* b1p = (const float4*)(B1 + ((size_t)e * FF + f) * RR);
      const float4* b3p = (const float4*)(B3 + ((size_t)e * FF + f) * RR);
      float l1 = 0.f, l3 = 0.f;
#pragma unroll
      for (int qq = 0; qq < 8; qq++) {
        float4 v1 = b1p[qq], v3 = b3p[qq];
        const float* s1 = &sa1[k * 32 + qq * 4];
        const float* s3 = &sa3[k * 32 + qq * 4];
        l1 += v1.x * s1[0] + v1.y * s1[1] + v1.z * s1[2] + v1.w * s1[3];
        l3 += v3.x * s3[0] + v3.y * s3[1] + v3.z * s3[2] + v3.w * s3[3];
      }
      float x1 = y1 + l1, x3 = y3 + l3;
      float sig = 1.f / (1.f + __expf(-x1));
      X2[(size_t)k * TT * FF + (size_t)t * FF + f] = f2bf(x1 * sig * x3);
    }
  }
}

// ---------------- a2 for selected experts ----------------
__global__ __launch_bounds__(256) void a2_kernel(
    const u16* __restrict__ X2, const float* __restrict__ A2,
    const int* __restrict__ sel, float* __restrict__ a2o) {
  int t = blockIdx.x >> 1, k = blockIdx.x & 1;
  int e = sel[t * 2 + k] & 7;
  __shared__ __align__(16) float sxf[FF];  // 28 KB
  const u16* src = X2 + (size_t)k * TT * FF + (size_t)t * FF;
  for (int i = threadIdx.x; i < FF / 8; i += 256) {
    uint4 v = ((const uint4*)src)[i];
    float* d = &sxf[i * 8];
    d[0] = bf2f((u16)(v.x & 0xFFFF)); d[1] = bf2f((u16)(v.x >> 16));
    d[2] = bf2f((u16)(v.y & 0xFFFF)); d[3] = bf2f((u16)(v.y >> 16));
    d[4] = bf2f((u16)(v.z & 0xFFFF)); d[5] = bf2f((u16)(v.z >> 16));
    d[6] = bf2f((u16)(v.w & 0xFFFF)); d[7] = bf2f((u16)(v.w >> 16));
  }
  __syncthreads();
  int wave = threadIdx.x >> 6, lane = threadIdx.x & 63;
  for (int j = 0; j < 8; j++) {
    int r = wave * 8 + j;
    const float* Arow = A2 + ((size_t)e * RR + r) * FF;
    float s = 0.f;
#pragma unroll
    for (int i = 0; i < 28; i++) {        // FF/4/64 = 28 float4 iters
      int c = lane + 64 * i;              // < 1792
      float4 a = ((const float4*)Arow)[c];
      const float* b = &sxf[c * 4];
      s += a.x * b[0] + a.y * b[1] + a.z * b[2] + a.w * b[3];
    }
    for (int off = 32; off; off >>= 1) s += __shfl_down(s, off);
    if (lane == 0) a2o[((size_t)t * KT + k) * RR + r] = s;
  }
}

// ---------------- out = sum_k rw_k * (down_k + B2[e]*a2)  (f32 out) ----------------
__global__ __launch_bounds__(256) void final_kernel(
    const float* __restrict__ down, const float* __restrict__ B2,
    const float* __restrict__ a2, const int* __restrict__ sel,
    const float* __restrict__ rw, float* __restrict__ out) {
  int t = blockIdx.x;
  __shared__ float sa2[64], srw[2];
  __shared__ int se[2];
  if (threadIdx.x < 64) sa2[threadIdx.x] = a2[(size_t)t * 64 + threadIdx.x];
  if (threadIdx.x < 2) {
    se[threadIdx.x] = sel[t * 2 + threadIdx.x] & 7;
    srw[threadIdx.x] = rw[t * 2 + threadIdx.x];
  }
  __syncthreads();
  for (int h = threadIdx.x; h < HH; h += 256) {
    float o = 0.f;
#pragma unroll
    for (int k = 0; k < 2; k++) {
      int e = se[k];
      float d = down[(size_t)k * TT * HH + (size_t)t * HH + h];
      const float4* bp = (const float4*)(B2 + ((size_t)e * HH + h) * RR);
      float l2 = 0.f;
#pragma unroll
      for (int qq = 0; qq < 8; qq++) {
        float4 v = bp[qq];
        const float* s2 = &sa2[k * 32 + qq * 4];
        l2 += v.x * s2[0] + v.y * s2[1] + v.z * s2[2] + v.w * s2[3];
      }
      o += srw[k] * (d + l2);
    }
    out[(size_t)t * HH + h] = o;
  }
}

extern "C" void kernel_launch(void* const* d_in, const int* in_sizes, int n_in,
                              void* d_out, int out_size, void* d_ws, size_t ws_size,
                              hipStream_t stream) {
  if (n_in < 11) return;
  const float* X  = (const float*)d_in[0];
  const float* Wg = (const float*)d_in[1];
  const float* W1 = (const float*)d_in[2];
  const float* W2 = (const float*)d_in[3];
  const float* W3 = (const float*)d_in[4];
  const float* A1 = (const float*)d_in[5];
  const float* B1 = (const float*)d_in[6];
  const float* A2 = (const float*)d_in[7];
  const float* B2 = (const float*)d_in[8];
  const float* A3 = (const float*)d_in[9];
  const float* B3 = (const float*)d_in[10];
  float* out = (float*)d_out;

  char* ws = (char*)d_ws;
  size_t off = 0;
  auto take = [&](size_t bytes) -> void* {
    void* p = ws + off;
    off += (bytes + 255) & ~(size_t)255;
    return p;
  };
  u16*   Xb   = (u16*)take((size_t)TT * HH * 2);
  u16*   W1b  = (u16*)take((size_t)FF * HH * 2);
  u16*   W3b  = (u16*)take((size_t)FF * HH * 2);
  u16*   W2b  = (u16*)take((size_t)HH * FF * 2);
  int*   sel  = (int*)take((size_t)TT * KT * 4);
  float* rw   = (float*)take((size_t)TT * KT * 4);
  float* a1b  = (float*)take((size_t)TT * KT * RR * 4);
  float* a3b  = (float*)take((size_t)TT * KT * RR * 4);
  float* a2b  = (float*)take((size_t)TT * KT * RR * 4);
  u16*   Y1   = (u16*)take((size_t)TT * FF * 2);
  u16*   Y3   = (u16*)take((size_t)TT * FF * 2);
  u16*   X2   = (u16*)take((size_t)KT * TT * FF * 2);
  float* down = (float*)take((size_t)KT * TT * HH * 4);
  if (off > ws_size) return;

  cvt_kernel<<<2048, 256, 0, stream>>>(X,  Xb,  TT * HH / 4);
  cvt_kernel<<<2048, 256, 0, stream>>>(W1, W1b, FF * HH / 4);
  cvt_kernel<<<2048, 256, 0, stream>>>(W3, W3b, FF * HH / 4);
  cvt_kernel<<<2048, 256, 0, stream>>>(W2, W2b, HH * FF / 4);
  gating_kernel<<<TT, 64, 0, stream>>>(X, Wg, sel, rw);
  a13_kernel<<<TT * KT, 256, 0, stream>>>(X, A1, A3, sel, a1b, a3b);
  gemm_bt<<<dim3(FF / 128, TT / 128, 2), 256, 0, stream>>>(
      Xb, Xb, W1b, W3b, Y1, Y3, (float*)nullptr, (float*)nullptr, FF, HH, 1);
  silu_kernel<<<TT, 256, 0, stream>>>(Y1, Y3, B1, B3, a1b, a3b, sel, X2);
  gemm_bt<<<dim3(HH / 128, TT / 128, 2), 256, 0, stream>>>(
      X2, X2 + (size_t)TT * FF, W2b, W2b, (u16*)nullptr, (u16*)nullptr,
      down, down + (size_t)TT * HH, HH, FF, 0);
  a2_kernel<<<TT * KT, 256, 0, stream>>>(X2, A2, sel, a2b);
  final_kernel<<<TT, 256, 0, stream>>>(down, B2, a2b, sel, rw, out);
}

// Round 5
// 2007.290 us; speedup vs baseline: 1.3495x; 1.3495x over previous
//
#include <hip/hip_runtime.h>

typedef unsigned short u16;
typedef unsigned int u32;
typedef __attribute__((ext_vector_type(4))) float f32x4;
typedef __attribute__((ext_vector_type(8))) short short8;  // bf16 bits in i16 lanes

constexpr int TT = 2048;   // tokens = B*S
constexpr int HH = 2048;   // hidden
constexpr int FF = 7168;   // ffn
constexpr int RR = 32;     // lora rank
constexpr int KT = 2;      // top-k
constexpr int NA1 = FF + 256;   // 7424: W1/W3 aug N (A1flat/A3flat appended)
constexpr int NA2 = HH + 256;   // 2304: W2 aug N (A2flat appended)

__device__ __forceinline__ float bf2f(u16 v) {
  union { u32 u; float f; } w; w.u = ((u32)v) << 16; return w.f;
}
__device__ __forceinline__ u16 f2bf(float f) {
  union { float f; u32 u; } w; w.f = f;
  u32 u = w.u;
  return (u16)((u + 0x7FFFu + ((u >> 16) & 1u)) >> 16);
}

// ---------------- f32 -> bf16 conversion (grid-stride, float4) ----------------
__global__ __launch_bounds__(256) void cvt_kernel(
    const float* __restrict__ src, u16* __restrict__ dst, int n4) {
  int stride = gridDim.x * 256;
  for (int i = blockIdx.x * 256 + threadIdx.x; i < n4; i += stride) {
    float4 v = ((const float4*)src)[i];
    ushort4 o;
    o.x = f2bf(v.x); o.y = f2bf(v.y); o.z = f2bf(v.z); o.w = f2bf(v.w);
    ((ushort4*)dst)[i] = o;
  }
}

// ---------------- repack B [E, Fdim, R] f32 -> Bm [Fdim, E*R] bf16 ----------------
__global__ __launch_bounds__(256) void repackB_kernel(
    const float* __restrict__ B, u16* __restrict__ Bm, int Fdim) {
  int n = Fdim * 256;
  int stride = gridDim.x * 256;
  for (int i = blockIdx.x * 256 + threadIdx.x; i < n; i += stride) {
    int f = i >> 8, c = i & 255, e = c >> 5, r = c & 31;
    Bm[i] = f2bf(B[((size_t)e * Fdim + f) * RR + r]);
  }
}

// ---------------- gating: logits -> top2 -> weights (f32 exact) ----------------
__global__ __launch_bounds__(64) void gating_kernel(
    const float* __restrict__ X, const float* __restrict__ Wg,
    int* __restrict__ sel, float* __restrict__ rw) {
  int t = blockIdx.x;
  int lane = threadIdx.x;
  const float* x = X + (size_t)t * HH;
  float acc[8] = {};
  for (int h = lane; h < HH; h += 64) {
    float xv = x[h];
#pragma unroll
    for (int e = 0; e < 8; e++) acc[e] += xv * Wg[e * HH + h];
  }
#pragma unroll
  for (int e = 0; e < 8; e++)
    for (int off = 32; off; off >>= 1) acc[e] += __shfl_down(acc[e], off);
  if (lane == 0) {
    int b0 = 0; float l0 = acc[0];
    for (int e = 1; e < 8; e++) if (acc[e] > l0) { l0 = acc[e]; b0 = e; }
    int b1 = -1; float l1 = 0.f;
    for (int e = 0; e < 8; e++) {
      if (e == b0) continue;
      if (b1 < 0 || acc[e] > l1) { l1 = acc[e]; b1 = e; }
    }
    float p = 1.f / (1.f + __expf(l1 - l0));
    sel[t * 2 + 0] = b0; sel[t * 2 + 1] = b1;
    rw[t * 2 + 0] = p;   rw[t * 2 + 1] = 1.f - p;
  }
}

// ---------------- MFMA GEMM: C[M,N] = A[M,K] * Bm[N,K]^T (bf16 in) ----------------
__global__ __launch_bounds__(256) void gemm_bt(
    const u16* A0, const u16* A1p,
    const u16* B0, const u16* B1p,
    u16* Cb0, u16* Cb1, float* Cf0, float* Cf1,
    int N, int Kd, int out_bf16) {
  const u16* A  = blockIdx.z ? A1p : A0;
  const u16* Bm = blockIdx.z ? B1p : B0;
  u16* Cb       = blockIdx.z ? Cb1 : Cb0;
  float* Cf     = blockIdx.z ? Cf1 : Cf0;

  __shared__ __align__(16) u16 As[128 * 64];
  __shared__ __align__(16) u16 Bs[128 * 64];

  int tid = threadIdx.x;
  int tn = blockIdx.x * 128;
  int tm = blockIdx.y * 128;
  int lane = tid & 63;
  int wave = tid >> 6;
  int wm = (wave >> 1) * 64, wn = (wave & 1) * 64;
  const int r15 = lane & 15, q = lane >> 4;

  f32x4 acc[4][4] = {};

  for (int k0 = 0; k0 < Kd; k0 += 64) {
    uint4 ra[4], rb[4];
#pragma unroll
    for (int it = 0; it < 4; it++) {
      int c = it * 256 + tid;
      int row = c >> 3, c8 = c & 7;
      int scol = ((c8 ^ (row & 7)) << 3);
      ra[it] = *(const uint4*)(A + (size_t)(tm + row) * Kd + (k0 + scol));
      rb[it] = *(const uint4*)(Bm + (size_t)(tn + row) * Kd + (k0 + scol));
    }
    __syncthreads();
#pragma unroll
    for (int it = 0; it < 4; it++) {
      int c = it * 256 + tid;
      *(uint4*)(As + c * 8) = ra[it];
      *(uint4*)(Bs + c * 8) = rb[it];
    }
    __syncthreads();
#pragma unroll
    for (int kk = 0; kk < 2; kk++) {
      short8 af[4], bfr[4];
#pragma unroll
      for (int mi = 0; mi < 4; mi++) {
        int row = wm + mi * 16 + r15;
        int kc = (kk * 4 + q) ^ (row & 7);
        af[mi] = *(const short8*)(As + row * 64 + kc * 8);
      }
#pragma unroll
      for (int ni = 0; ni < 4; ni++) {
        int row = wn + ni * 16 + r15;
        int kc = (kk * 4 + q) ^ (row & 7);
        bfr[ni] = *(const short8*)(Bs + row * 64 + kc * 8);
      }
#pragma unroll
      for (int mi = 0; mi < 4; mi++)
#pragma unroll
        for (int ni = 0; ni < 4; ni++)
          acc[mi][ni] = __builtin_amdgcn_mfma_f32_16x16x32_bf16(af[mi], bfr[ni], acc[mi][ni], 0, 0, 0);
    }
  }
#pragma unroll
  for (int mi = 0; mi < 4; mi++)
#pragma unroll
    for (int ni = 0; ni < 4; ni++)
#pragma unroll
      for (int i = 0; i < 4; i++) {
        int r = tm + wm + mi * 16 + q * 4 + i;
        int cc = tn + wn + ni * 16 + r15;
        float v = acc[mi][ni][i];
        if (out_bf16) Cb[(size_t)r * N + cc] = f2bf(v);
        else          Cf[(size_t)r * N + cc] = v;
      }
}

// ---------------- mask/expand: a1_all/a3_all (Y-aug cols) -> zero-padded ahat ----------------
__global__ __launch_bounds__(256) void mask13_kernel(
    const u16* __restrict__ Y1, const u16* __restrict__ Y3,
    const int* __restrict__ sel, u16* __restrict__ ah1, u16* __restrict__ ah3) {
  int tk = blockIdx.x;
  int t = tk >> 1;
  int e = sel[tk] & 7;
  int c = threadIdx.x;
  bool in = (c >> 5) == e;
  ah1[(size_t)tk * 256 + c] = in ? Y1[(size_t)t * NA1 + FF + c] : (u16)0;
  ah3[(size_t)tk * 256 + c] = in ? Y3[(size_t)t * NA1 + FF + c] : (u16)0;
}

__global__ __launch_bounds__(256) void mask2_kernel(
    const u16* __restrict__ down_aug, const int* __restrict__ sel,
    u16* __restrict__ ah2) {
  int tk = blockIdx.x;
  int t = tk >> 1, k = tk & 1;
  int e = sel[tk] & 7;
  int c = threadIdx.x;
  ah2[(size_t)tk * 256 + c] =
      ((c >> 5) == e) ? down_aug[((size_t)k * TT + t) * NA2 + HH + c] : (u16)0;
}

// ---------------- fused lora1/lora3 GEMM + add-base + silu -> X2 ----------------
// C1 = ah1[4096,256] * Bm1[7168,256]^T ; C3 likewise; then
// X2[k,t,f] = silu(Y1[t,f]+C1[tk,f]) * (Y3[t,f]+C3[tk,f]),  tk = t*2+k.
// B-tiles staged in LDS (swizzled); A-fragments read direct from global (L2-resident, 2 MB).
__global__ __launch_bounds__(256) void lora_silu_kernel(
    const u16* __restrict__ ah1, const u16* __restrict__ ah3,
    const u16* __restrict__ Bm1, const u16* __restrict__ Bm3,
    const u16* __restrict__ Y1, const u16* __restrict__ Y3,
    u16* __restrict__ X2) {
  __shared__ __align__(16) u16 Bs1[128 * 64];
  __shared__ __align__(16) u16 Bs3[128 * 64];
  int tid = threadIdx.x;
  int tn = blockIdx.x * 128;   // f tile
  int tm = blockIdx.y * 128;   // slot (tk) tile
  int lane = tid & 63, wave = tid >> 6;
  int wm = (wave >> 1) * 64, wn = (wave & 1) * 64;
  const int r15 = lane & 15, q = lane >> 4;

  f32x4 acc1[4][4] = {}, acc3[4][4] = {};

  for (int k0 = 0; k0 < 256; k0 += 64) {
    uint4 rb1[4], rb3[4];
#pragma unroll
    for (int it = 0; it < 4; it++) {
      int c = it * 256 + tid;
      int row = c >> 3, c8 = c & 7;
      int scol = ((c8 ^ (row & 7)) << 3);
      rb1[it] = *(const uint4*)(Bm1 + (size_t)(tn + row) * 256 + (k0 + scol));
      rb3[it] = *(const uint4*)(Bm3 + (size_t)(tn + row) * 256 + (k0 + scol));
    }
    __syncthreads();
#pragma unroll
    for (int it = 0; it < 4; it++) {
      int c = it * 256 + tid;
      *(uint4*)(Bs1 + c * 8) = rb1[it];
      *(uint4*)(Bs3 + c * 8) = rb3[it];
    }
    __syncthreads();
#pragma unroll
    for (int kk = 0; kk < 2; kk++) {
      short8 a1f[4], a3f[4], b1f[4], b3f[4];
#pragma unroll
      for (int mi = 0; mi < 4; mi++) {
        int row = tm + wm + mi * 16 + r15;
        size_t o = (size_t)row * 256 + k0 + (kk * 4 + q) * 8;
        a1f[mi] = *(const short8*)(ah1 + o);
        a3f[mi] = *(const short8*)(ah3 + o);
      }
#pragma unroll
      for (int ni = 0; ni < 4; ni++) {
        int row = wn + ni * 16 + r15;
        int kc = (kk * 4 + q) ^ (row & 7);
        b1f[ni] = *(const short8*)(Bs1 + row * 64 + kc * 8);
        b3f[ni] = *(const short8*)(Bs3 + row * 64 + kc * 8);
      }
#pragma unroll
      for (int mi = 0; mi < 4; mi++)
#pragma unroll
        for (int ni = 0; ni < 4; ni++) {
          acc1[mi][ni] = __builtin_amdgcn_mfma_f32_16x16x32_bf16(a1f[mi], b1f[ni], acc1[mi][ni], 0, 0, 0);
          acc3[mi][ni] = __builtin_amdgcn_mfma_f32_16x16x32_bf16(a3f[mi], b3f[ni], acc3[mi][ni], 0, 0, 0);
        }
    }
    __syncthreads();
  }
#pragma unroll
  for (int mi = 0; mi < 4; mi++)
#pragma unroll
    for (int ni = 0; ni < 4; ni++)
#pragma unroll
      for (int i = 0; i < 4; i++) {
        int row = tm + wm + mi * 16 + q * 4 + i;   // tk slot
        int f = tn + wn + ni * 16 + r15;
        int t = row >> 1, k = row & 1;
        float x1 = bf2f(Y1[(size_t)t * NA1 + f]) + acc1[mi][ni][i];
        float x3 = bf2f(Y3[(size_t)t * NA1 + f]) + acc3[mi][ni][i];
        float sig = 1.f / (1.f + __expf(-x1));
        X2[((size_t)k * TT + t) * FF + f] = f2bf(x1 * sig * x3);
      }
}

// ---------------- out = sum_k rw_k * (down_k + lora2_k)  (f32 out) ----------------
__global__ __launch_bounds__(256) void final_kernel(
    const u16* __restrict__ down_aug, const float* __restrict__ L2b,
    const float* __restrict__ rw, float* __restrict__ out) {
  int t = blockIdx.x;
  float r0 = rw[t * 2], r1 = rw[t * 2 + 1];
  for (int h = threadIdx.x; h < HH; h += 256) {
    float d0 = bf2f(down_aug[(size_t)t * NA2 + h]);
    float d1 = bf2f(down_aug[((size_t)TT + t) * NA2 + h]);
    float l0 = L2b[(size_t)(t * 2) * HH + h];
    float l1 = L2b[(size_t)(t * 2 + 1) * HH + h];
    out[(size_t)t * HH + h] = r0 * (d0 + l0) + r1 * (d1 + l1);
  }
}

extern "C" void kernel_launch(void* const* d_in, const int* in_sizes, int n_in,
                              void* d_out, int out_size, void* d_ws, size_t ws_size,
                              hipStream_t stream) {
  if (n_in < 11) return;
  const float* X  = (const float*)d_in[0];
  const float* Wg = (const float*)d_in[1];
  const float* W1 = (const float*)d_in[2];
  const float* W2 = (const float*)d_in[3];
  const float* W3 = (const float*)d_in[4];
  const float* A1 = (const float*)d_in[5];
  const float* B1 = (const float*)d_in[6];
  const float* A2 = (const float*)d_in[7];
  const float* B2 = (const float*)d_in[8];
  const float* A3 = (const float*)d_in[9];
  const float* B3 = (const float*)d_in[10];
  float* out = (float*)d_out;

  char* ws = (char*)d_ws;
  size_t off = 0;
  auto take = [&](size_t bytes) -> void* {
    void* p = ws + off;
    off += (bytes + 255) & ~(size_t)255;
    return p;
  };
  u16*   Xb     = (u16*)take((size_t)TT * HH * 2);
  u16*   W1augb = (u16*)take((size_t)NA1 * HH * 2);   // rows: W1 | A1flat
  u16*   W3augb = (u16*)take((size_t)NA1 * HH * 2);   // rows: W3 | A3flat
  u16*   W2augb = (u16*)take((size_t)NA2 * FF * 2);   // rows: W2 | A2flat
  u16*   Bm1    = (u16*)take((size_t)FF * 256 * 2);
  u16*   Bm3    = (u16*)take((size_t)FF * 256 * 2);
  u16*   Bm2    = (u16*)take((size_t)HH * 256 * 2);
  u16*   Y1aug  = (u16*)take((size_t)TT * NA1 * 2);
  u16*   Y3aug  = (u16*)take((size_t)TT * NA1 * 2);
  u16*   ah1    = (u16*)take((size_t)TT * KT * 256 * 2);
  u16*   ah3    = (u16*)take((size_t)TT * KT * 256 * 2);
  u16*   ah2    = (u16*)take((size_t)TT * KT * 256 * 2);
  u16*   X2     = (u16*)take((size_t)KT * TT * FF * 2);
  int*   sel    = (int*)take((size_t)TT * KT * 4);
  float* rw     = (float*)take((size_t)TT * KT * 4);
  if (off > ws_size) return;
  // Aliases into regions that are dead by the time these are written:
  // down_aug (2*2048*2304*2 = 18.9 MB) overlays W1augb (dead after GEMM13).
  // L2b (4096*2048*4 = 33.6 MB) overlays W3augb + start of W2augb (both dead after down GEMM).
  u16*   down_aug = W1augb;
  float* L2b      = (float*)W3augb;

  // --- precompute: bf16 casts + repacks (weights are reused many times) ---
  cvt_kernel<<<1024, 256, 0, stream>>>(X,  Xb, TT * HH / 4);
  cvt_kernel<<<1024, 256, 0, stream>>>(W1, W1augb, FF * HH / 4);
  cvt_kernel<<<1024, 256, 0, stream>>>(A1, W1augb + (size_t)FF * HH, 256 * HH / 4);
  cvt_kernel<<<1024, 256, 0, stream>>>(W3, W3augb, FF * HH / 4);
  cvt_kernel<<<1024, 256, 0, stream>>>(A3, W3augb + (size_t)FF * HH, 256 * HH / 4);
  cvt_kernel<<<1024, 256, 0, stream>>>(W2, W2augb, HH * FF / 4);
  cvt_kernel<<<1024, 256, 0, stream>>>(A2, W2augb + (size_t)HH * FF, 256 * FF / 4);
  repackB_kernel<<<1024, 256, 0, stream>>>(B1, Bm1, FF);
  repackB_kernel<<<1024, 256, 0, stream>>>(B3, Bm3, FF);
  repackB_kernel<<<1024, 256, 0, stream>>>(B2, Bm2, HH);
  gating_kernel<<<TT, 64, 0, stream>>>(X, Wg, sel, rw);

  // --- Y1aug/Y3aug = Xb @ [W1|A1flat]^T, [W3|A3flat]^T  (a1_all/a3_all free in cols F..) ---
  gemm_bt<<<dim3(NA1 / 128, TT / 128, 2), 256, 0, stream>>>(
      Xb, Xb, W1augb, W3augb, Y1aug, Y3aug, nullptr, nullptr, NA1, HH, 1);
  mask13_kernel<<<TT * KT, 256, 0, stream>>>(Y1aug, Y3aug, sel, ah1, ah3);
  // --- X2 = silu(Y1 + ah1@Bm1^T) * (Y3 + ah3@Bm3^T) ---
  lora_silu_kernel<<<dim3(FF / 128, TT * KT / 128), 256, 0, stream>>>(
      ah1, ah3, Bm1, Bm3, Y1aug, Y3aug, X2);
  // --- down_aug = X2[k] @ [W2|A2flat]^T  (a2_all free in cols H..) ---
  gemm_bt<<<dim3(NA2 / 128, TT / 128, 2), 256, 0, stream>>>(
      X2, X2 + (size_t)TT * FF, W2augb, W2augb,
      down_aug, down_aug + (size_t)TT * NA2, nullptr, nullptr, NA2, FF, 1);
  mask2_kernel<<<TT * KT, 256, 0, stream>>>(down_aug, sel, ah2);
  // --- L2b = ah2 @ Bm2^T ---
  gemm_bt<<<dim3(HH / 128, TT * KT / 128, 1), 256, 0, stream>>>(
      ah2, ah2, Bm2, Bm2, nullptr, nullptr, L2b, L2b, HH, 256, 0);
  final_kernel<<<TT, 256, 0, stream>>>(down_aug, L2b, rw, out);
}